// Round 1
// baseline (1183.729 us; speedup 1.0000x reference)
//
#include <hip/hip_runtime.h>

#define NDIM 512
#define NN   (NDIM * NDIM)   // 262144 positions

// Workspace layout (floats):
//   planes 0..31   : a1[d][i][k] = g[i][k][d]        (g channels   0..31)
//   planes 32..63  : b1[d][j][k] = g[j][k][32+d]     (g channels  32..63)
//   planes 64..95  : a2[d][i][k] = g[k][i][64+d]     (g channels  64..95, transposed store)
//   planes 96..127 : b2[d][j][k] = g[k][j][96+d]     (g channels  96..127, transposed store)
//   planes 128..191: t[dd][i][j]                     (einsum output, 64 channels)
// Total: 192 planes * 1 MiB = 192 MiB.

// ---------------------------------------------------------------------------
// Stage 1: LN1 + pi/gi matvecs + sigmoid gate + mask -> permuted g planes
// One thread per position, 16x16 position tile per 256-thread block.
// Weights read via wave-uniform addresses (compiler emits s_load; broadcast).
// ---------------------------------------------------------------------------
__global__ __launch_bounds__(256, 2)
void k_stage1(const float* __restrict__ x, const float* __restrict__ mask,
              const float* __restrict__ ln1_w, const float* __restrict__ ln1_b,
              const float* __restrict__ pi_w, const float* __restrict__ pi_b,
              const float* __restrict__ gi_w, const float* __restrict__ gi_b,
              float* __restrict__ ws)
{
    const int tid = threadIdx.x;
    const int r = ((blockIdx.x >> 5) << 4) + (tid >> 4);
    const int c = ((blockIdx.x & 31) << 4) + (tid & 15);
    const long pos = (long)r * NDIM + c;

    // Load the 128-float input row into registers, accumulate sum.
    float h[128];
    const float4* xp = (const float4*)(x + pos * 128);
    float s = 0.f;
#pragma unroll
    for (int q = 0; q < 32; ++q) {
        float4 v = xp[q];
        h[4*q+0] = v.x; h[4*q+1] = v.y; h[4*q+2] = v.z; h[4*q+3] = v.w;
        s += v.x + v.y + v.z + v.w;
    }
    const float mu = s * (1.f / 128.f);
    float vs = 0.f;
#pragma unroll
    for (int k = 0; k < 128; ++k) { float d = h[k] - mu; vs += d * d; }
    const float rstd = rsqrtf(vs * (1.f / 128.f) + 1e-5f);
#pragma unroll
    for (int k = 0; k < 128; ++k)
        h[k] = (h[k] - mu) * rstd * ln1_w[k] + ln1_b[k];

    const float mval = mask[pos];

    // 16 chunks of 8 paired (pi, gi) outputs.
#pragma unroll 1
    for (int oc = 0; oc < 16; ++oc) {
        const int o0 = oc * 8;
        float ap[8], ag[8];
#pragma unroll
        for (int j = 0; j < 8; ++j) { ap[j] = pi_b[o0 + j]; ag[j] = gi_b[o0 + j]; }
#pragma unroll
        for (int k = 0; k < 128; ++k) {
            const float hk = h[k];
            const float* pw = pi_w + k * 128 + o0;   // uniform -> s_load
            const float* gw = gi_w + k * 128 + o0;
#pragma unroll
            for (int j = 0; j < 8; ++j) ap[j] = fmaf(hk, pw[j], ap[j]);
#pragma unroll
            for (int j = 0; j < 8; ++j) ag[j] = fmaf(hk, gw[j], ag[j]);
        }
#pragma unroll
        for (int j = 0; j < 8; ++j) {
            const int o = o0 + j;                 // g channel 0..127 == plane index
            const float g = ap[j] * (1.f / (1.f + __expf(-ag[j]))) * mval;
            long addr;
            if (o < 64) addr = (long)o * NN + (long)r * NDIM + c;        // a1/b1
            else        addr = (long)o * NN + (long)c * NDIM + r;        // a2/b2 transposed
            ws[addr] = g;
        }
    }
}

// ---------------------------------------------------------------------------
// Triangular einsums as 64 independent 512x512x512 NT-GEMMs (one per channel).
// C[i][j] = sum_k P[i][k] * Q[j][k].  128x128 tile, BK=16, 8x8 per thread.
// ---------------------------------------------------------------------------
__global__ __launch_bounds__(256, 4)
void k_einsum(const float* __restrict__ wsg, float* __restrict__ wst)
{
    const int bi = blockIdx.x, bj = blockIdx.y, dd = blockIdx.z;
    const int pbase = (dd < 32) ? dd : dd + 32;
    const float* __restrict__ P = wsg + (long)pbase * NN;
    const float* __restrict__ Q = wsg + (long)(pbase + 32) * NN;
    float* __restrict__ T = wst + (long)dd * NN;

    __shared__ float Pl[16][128];
    __shared__ float Ql[16][128];

    const int tid = threadIdx.x;
    const int ti = tid & 15, tj = tid >> 4;
    const int i0 = bi * 128, j0 = bj * 128;
    const int srow = tid >> 1;           // 0..127
    const int sh   = (tid & 1) * 8;      // 0 or 8

    float acc[8][8];
#pragma unroll
    for (int a = 0; a < 8; ++a)
#pragma unroll
        for (int b = 0; b < 8; ++b) acc[a][b] = 0.f;

    for (int kb = 0; kb < 32; ++kb) {
        const int k0 = kb * 16;
        const float4 p0 = *(const float4*)(P + (long)(i0 + srow) * NDIM + k0 + sh);
        const float4 p1 = *(const float4*)(P + (long)(i0 + srow) * NDIM + k0 + sh + 4);
        const float4 q0 = *(const float4*)(Q + (long)(j0 + srow) * NDIM + k0 + sh);
        const float4 q1 = *(const float4*)(Q + (long)(j0 + srow) * NDIM + k0 + sh + 4);
        __syncthreads();   // previous iter's compute done before overwrite
        Pl[sh+0][srow]=p0.x; Pl[sh+1][srow]=p0.y; Pl[sh+2][srow]=p0.z; Pl[sh+3][srow]=p0.w;
        Pl[sh+4][srow]=p1.x; Pl[sh+5][srow]=p1.y; Pl[sh+6][srow]=p1.z; Pl[sh+7][srow]=p1.w;
        Ql[sh+0][srow]=q0.x; Ql[sh+1][srow]=q0.y; Ql[sh+2][srow]=q0.z; Ql[sh+3][srow]=q0.w;
        Ql[sh+4][srow]=q1.x; Ql[sh+5][srow]=q1.y; Ql[sh+6][srow]=q1.z; Ql[sh+7][srow]=q1.w;
        __syncthreads();
#pragma unroll
        for (int k = 0; k < 16; ++k) {
            const float4 pa = *(const float4*)&Pl[k][ti * 4];
            const float4 pb = *(const float4*)&Pl[k][64 + ti * 4];
            const float4 qa = *(const float4*)&Ql[k][tj * 4];
            const float4 qb = *(const float4*)&Ql[k][64 + tj * 4];
            const float pv[8] = {pa.x, pa.y, pa.z, pa.w, pb.x, pb.y, pb.z, pb.w};
            const float qv[8] = {qa.x, qa.y, qa.z, qa.w, qb.x, qb.y, qb.z, qb.w};
#pragma unroll
            for (int a = 0; a < 8; ++a)
#pragma unroll
                for (int b = 0; b < 8; ++b)
                    acc[a][b] = fmaf(pv[a], qv[b], acc[a][b]);
        }
    }

#pragma unroll
    for (int a = 0; a < 8; ++a) {
        const int i = (a < 4) ? (ti * 4 + a) : (64 + ti * 4 + a - 4);
        float4 v0, v1;
        v0.x=acc[a][0]; v0.y=acc[a][1]; v0.z=acc[a][2]; v0.w=acc[a][3];
        v1.x=acc[a][4]; v1.y=acc[a][5]; v1.z=acc[a][6]; v1.w=acc[a][7];
        *(float4*)(T + (long)(i0 + i) * NDIM + j0 + tj * 4)      = v0;
        *(float4*)(T + (long)(i0 + i) * NDIM + j0 + 64 + tj * 4) = v1;
    }
}

// ---------------------------------------------------------------------------
// Stage 2: gather 64 t-planes, LN2, po/go matvecs, gate, mask -> output
// One thread per position; plane gathers coalesce across the wave.
// ---------------------------------------------------------------------------
__global__ __launch_bounds__(256, 3)
void k_stage2(const float* __restrict__ wst, const float* __restrict__ mask,
              const float* __restrict__ ln2_w, const float* __restrict__ ln2_b,
              const float* __restrict__ po_w, const float* __restrict__ po_b,
              const float* __restrict__ go_w, const float* __restrict__ go_b,
              float* __restrict__ out)
{
    const long pos = (long)blockIdx.x * 256 + threadIdx.x;

    float t[64];
    float s = 0.f;
#pragma unroll
    for (int d = 0; d < 64; ++d) { t[d] = wst[(long)d * NN + pos]; s += t[d]; }
    const float mu = s * (1.f / 64.f);
    float vs = 0.f;
#pragma unroll
    for (int d = 0; d < 64; ++d) { float dv = t[d] - mu; vs += dv * dv; }
    const float rstd = rsqrtf(vs * (1.f / 64.f) + 1e-5f);
#pragma unroll
    for (int d = 0; d < 64; ++d) t[d] = (t[d] - mu) * rstd * ln2_w[d] + ln2_b[d];

    const float mval = mask[pos];
    float* op = out + pos * 128;

#pragma unroll 1
    for (int oc = 0; oc < 16; ++oc) {
        const int o0 = oc * 8;
        float ap[8], ag[8];
#pragma unroll
        for (int j = 0; j < 8; ++j) { ap[j] = po_b[o0 + j]; ag[j] = go_b[o0 + j]; }
#pragma unroll
        for (int k = 0; k < 64; ++k) {
            const float tk = t[k];
            const float* pw = po_w + k * 128 + o0;   // uniform -> s_load
            const float* gw = go_w + k * 128 + o0;
#pragma unroll
            for (int j = 0; j < 8; ++j) ap[j] = fmaf(tk, pw[j], ap[j]);
#pragma unroll
            for (int j = 0; j < 8; ++j) ag[j] = fmaf(tk, gw[j], ag[j]);
        }
        float4 v0, v1;
        float res[8];
#pragma unroll
        for (int j = 0; j < 8; ++j)
            res[j] = ap[j] * (1.f / (1.f + __expf(-ag[j]))) * mval;
        v0.x=res[0]; v0.y=res[1]; v0.z=res[2]; v0.w=res[3];
        v1.x=res[4]; v1.y=res[5]; v1.z=res[6]; v1.w=res[7];
        *(float4*)(op + o0)     = v0;
        *(float4*)(op + o0 + 4) = v1;
    }
}

// ---------------------------------------------------------------------------
extern "C" void kernel_launch(void* const* d_in, const int* in_sizes, int n_in,
                              void* d_out, int out_size, void* d_ws, size_t ws_size,
                              hipStream_t stream)
{
    const float* x     = (const float*)d_in[0];
    const float* mask  = (const float*)d_in[1];
    const float* ln1_w = (const float*)d_in[2];
    const float* ln1_b = (const float*)d_in[3];
    const float* pi_w  = (const float*)d_in[4];
    const float* pi_b  = (const float*)d_in[5];
    const float* gi_w  = (const float*)d_in[6];
    const float* gi_b  = (const float*)d_in[7];
    const float* ln2_w = (const float*)d_in[8];
    const float* ln2_b = (const float*)d_in[9];
    const float* po_w  = (const float*)d_in[10];
    const float* po_b  = (const float*)d_in[11];
    const float* go_w  = (const float*)d_in[12];
    const float* go_b  = (const float*)d_in[13];

    float* wsg = (float*)d_ws;                  // 128 g-planes
    float* wst = wsg + (long)128 * NN;          // 64 t-planes

    k_stage1<<<1024, 256, 0, stream>>>(x, mask, ln1_w, ln1_b,
                                       pi_w, pi_b, gi_w, gi_b, wsg);
    k_einsum<<<dim3(4, 4, 64), 256, 0, stream>>>(wsg, wst);
    k_stage2<<<1024, 256, 0, stream>>>(wst, mask, ln2_w, ln2_b,
                                       po_w, po_b, go_w, go_b, (float*)d_out);
}

// Round 2
// 684.990 us; speedup vs baseline: 1.7281x; 1.7281x over previous
//
#include <hip/hip_runtime.h>

#define NDIM 512
#define NN   (NDIM * NDIM)   // 262144 positions

// Workspace layout (floats):
//   wsg planes 0..63   : g[i][k][d] stored [i*512+k]          (a1,b1 channels 0..63)
//   wsg planes 64..127 : g[k][i][d] stored transposed [i? ]   (a2,b2: plane[c][ci*512+ri])
//   wst planes 0..63   : t[dd][i][j]                          (einsum output)
// Total 192 MiB.

__device__ __forceinline__ float sigmoidf_(float z) {
    return 1.f / (1.f + __expf(-z));
}

// ---------------------------------------------------------------------------
// Stage 1: fused LN1 + dual GEMM (pi,gi) + gate + mask -> permuted g planes.
// Block: 128-position tile x 64 output cols (grid.y picks col half).
// LDS: hT[128][128] transposed LN'd inputs + 2x K-slab weights (BK=32).
// Thread: 8 rows x (4 pi + 4 gi) cols; 64 FMA per 4 ds_read_b128.
// ---------------------------------------------------------------------------
__global__ __launch_bounds__(256, 2)
void k_stage1(const float* __restrict__ x, const float* __restrict__ mask,
              const float* __restrict__ ln1_w, const float* __restrict__ ln1_b,
              const float* __restrict__ pi_w, const float* __restrict__ pi_b,
              const float* __restrict__ gi_w, const float* __restrict__ gi_b,
              float* __restrict__ wsg)
{
    __shared__ float hT[128][128];   // [feat][pos-local]  (bank: 2-way max, free)
    __shared__ float Wp[32][64];
    __shared__ float Wg[32][64];

    const int tid = threadIdx.x;
    const long pos0 = (long)blockIdx.x * 128;
    const int o0 = blockIdx.y * 64;

    // Prefetch weight slab 0 into registers (overlaps LN phase).
    float4 pnext[2], gnext[2];
#pragma unroll
    for (int q = 0; q < 2; ++q) {
        const int u = q*256 + tid, kk = u >> 4, c4 = u & 15;
        pnext[q] = *(const float4*)(pi_w + kk*128 + o0 + c4*4);
        gnext[q] = *(const float4*)(gi_w + kk*128 + o0 + c4*4);
    }

    // --- LN phase: 2 threads per row, combine via shfl_xor(1) ---
    {
        const int r = tid >> 1, hf = tid & 1;
        const float* xr = x + (pos0 + r)*128 + hf*64;
        float v[64]; float s = 0.f;
#pragma unroll
        for (int q = 0; q < 16; ++q) {
            float4 t4 = ((const float4*)xr)[q];
            v[4*q+0]=t4.x; v[4*q+1]=t4.y; v[4*q+2]=t4.z; v[4*q+3]=t4.w;
            s += t4.x+t4.y+t4.z+t4.w;
        }
        s += __shfl_xor(s, 1);
        const float mu = s * (1.f/128.f);
        float vs = 0.f;
#pragma unroll
        for (int j = 0; j < 64; ++j) { float d = v[j]-mu; vs += d*d; }
        vs += __shfl_xor(vs, 1);
        const float rstd = rsqrtf(vs*(1.f/128.f) + 1e-5f);
#pragma unroll
        for (int j = 0; j < 64; ++j) {
            const int f = hf*64 + j;
            hT[f][r] = (v[j]-mu)*rstd*ln1_w[f] + ln1_b[f];
        }
    }

    float acc_p[8][4], acc_g[8][4];
#pragma unroll
    for (int a = 0; a < 8; ++a)
#pragma unroll
        for (int b = 0; b < 4; ++b) { acc_p[a][b]=0.f; acc_g[a][b]=0.f; }

    const int ti = tid >> 4, tj = tid & 15;

    for (int kb = 0; kb < 4; ++kb) {
        if (kb) __syncthreads();          // prior k-loop's slab reads done
#pragma unroll
        for (int q = 0; q < 2; ++q) {
            const int u = q*256 + tid, kk = u >> 4, c4 = u & 15;
            *(float4*)&Wp[kk][c4*4] = pnext[q];
            *(float4*)&Wg[kk][c4*4] = gnext[q];
        }
        __syncthreads();                  // slab (and, first iter, hT) visible
        if (kb < 3) {                     // prefetch next slab; waits under k-loop
#pragma unroll
            for (int q = 0; q < 2; ++q) {
                const int u = q*256 + tid, kk = u >> 4, c4 = u & 15;
                pnext[q] = *(const float4*)(pi_w + (kb*32+32+kk)*128 + o0 + c4*4);
                gnext[q] = *(const float4*)(gi_w + (kb*32+32+kk)*128 + o0 + c4*4);
            }
        }
        const int kbase = kb*32;
#pragma unroll
        for (int k = 0; k < 32; ++k) {
            const float4 a0 = *(const float4*)&hT[kbase+k][ti*8];
            const float4 a1 = *(const float4*)&hT[kbase+k][ti*8+4];
            const float4 pw = *(const float4*)&Wp[k][tj*4];
            const float4 gw = *(const float4*)&Wg[k][tj*4];
            const float av[8] = {a0.x,a0.y,a0.z,a0.w,a1.x,a1.y,a1.z,a1.w};
            const float pv[4] = {pw.x,pw.y,pw.z,pw.w};
            const float gv[4] = {gw.x,gw.y,gw.z,gw.w};
#pragma unroll
            for (int a = 0; a < 8; ++a) {
#pragma unroll
                for (int b = 0; b < 4; ++b) {
                    acc_p[a][b] = fmaf(av[a], pv[b], acc_p[a][b]);
                    acc_g[a][b] = fmaf(av[a], gv[b], acc_g[a][b]);
                }
            }
        }
    }

    // --- epilogue: bias, gate, mask, permuted stores ---
    float mv[8];
#pragma unroll
    for (int a = 0; a < 8; ++a) mv[a] = mask[pos0 + ti*8 + a];
    const int ribase = (int)(pos0 >> 9);
    const int ci0 = (int)(pos0 & 511);
#pragma unroll
    for (int b = 0; b < 4; ++b) {
        const int c = o0 + tj*4 + b;      // global channel 0..127 == plane idx
        const float pb = pi_b[c], gb = gi_b[c];
        float r8[8];
#pragma unroll
        for (int a = 0; a < 8; ++a)
            r8[a] = (acc_p[a][b] + pb) * sigmoidf_(acc_g[a][b] + gb) * mv[a];
        if (o0 == 0) {                    // planes 0..63: [i][k] layout, float4
            float* dst = wsg + (long)c*NN + pos0 + ti*8;
            *(float4*)dst     = make_float4(r8[0],r8[1],r8[2],r8[3]);
            *(float4*)(dst+4) = make_float4(r8[4],r8[5],r8[6],r8[7]);
        } else {                          // planes 64..127: transposed scatter
#pragma unroll
            for (int a = 0; a < 8; ++a)
                wsg[(long)c*NN + (long)(ci0 + ti*8 + a)*NDIM + ribase] = r8[a];
        }
    }
}

// ---------------------------------------------------------------------------
// Triangular einsums: 64 independent 512x512x512 NT-GEMMs (one per channel).
// ---------------------------------------------------------------------------
__global__ __launch_bounds__(256, 4)
void k_einsum(const float* __restrict__ wsg, float* __restrict__ wst)
{
    const int bi = blockIdx.x, bj = blockIdx.y, dd = blockIdx.z;
    const int pbase = (dd < 32) ? dd : dd + 32;
    const float* __restrict__ P = wsg + (long)pbase * NN;
    const float* __restrict__ Q = wsg + (long)(pbase + 32) * NN;
    float* __restrict__ T = wst + (long)dd * NN;

    __shared__ float Pl[16][128];
    __shared__ float Ql[16][128];

    const int tid = threadIdx.x;
    const int ti = tid & 15, tj = tid >> 4;
    const int i0 = bi * 128, j0 = bj * 128;
    const int srow = tid >> 1;
    const int sh   = (tid & 1) * 8;

    float acc[8][8];
#pragma unroll
    for (int a = 0; a < 8; ++a)
#pragma unroll
        for (int b = 0; b < 8; ++b) acc[a][b] = 0.f;

    for (int kb = 0; kb < 32; ++kb) {
        const int k0 = kb * 16;
        const float4 p0 = *(const float4*)(P + (long)(i0 + srow) * NDIM + k0 + sh);
        const float4 p1 = *(const float4*)(P + (long)(i0 + srow) * NDIM + k0 + sh + 4);
        const float4 q0 = *(const float4*)(Q + (long)(j0 + srow) * NDIM + k0 + sh);
        const float4 q1 = *(const float4*)(Q + (long)(j0 + srow) * NDIM + k0 + sh + 4);
        __syncthreads();
        Pl[sh+0][srow]=p0.x; Pl[sh+1][srow]=p0.y; Pl[sh+2][srow]=p0.z; Pl[sh+3][srow]=p0.w;
        Pl[sh+4][srow]=p1.x; Pl[sh+5][srow]=p1.y; Pl[sh+6][srow]=p1.z; Pl[sh+7][srow]=p1.w;
        Ql[sh+0][srow]=q0.x; Ql[sh+1][srow]=q0.y; Ql[sh+2][srow]=q0.z; Ql[sh+3][srow]=q0.w;
        Ql[sh+4][srow]=q1.x; Ql[sh+5][srow]=q1.y; Ql[sh+6][srow]=q1.z; Ql[sh+7][srow]=q1.w;
        __syncthreads();
#pragma unroll
        for (int k = 0; k < 16; ++k) {
            const float4 pa = *(const float4*)&Pl[k][ti * 4];
            const float4 pb = *(const float4*)&Pl[k][64 + ti * 4];
            const float4 qa = *(const float4*)&Ql[k][tj * 4];
            const float4 qb = *(const float4*)&Ql[k][64 + tj * 4];
            const float pv[8] = {pa.x, pa.y, pa.z, pa.w, pb.x, pb.y, pb.z, pb.w};
            const float qv[8] = {qa.x, qa.y, qa.z, qa.w, qb.x, qb.y, qb.z, qb.w};
#pragma unroll
            for (int a = 0; a < 8; ++a)
#pragma unroll
                for (int b = 0; b < 8; ++b)
                    acc[a][b] = fmaf(pv[a], qv[b], acc[a][b]);
        }
    }

#pragma unroll
    for (int a = 0; a < 8; ++a) {
        const int i = (a < 4) ? (ti * 4 + a) : (64 + ti * 4 + a - 4);
        float4 v0, v1;
        v0.x=acc[a][0]; v0.y=acc[a][1]; v0.z=acc[a][2]; v0.w=acc[a][3];
        v1.x=acc[a][4]; v1.y=acc[a][5]; v1.z=acc[a][6]; v1.w=acc[a][7];
        *(float4*)(T + (long)(i0 + i) * NDIM + j0 + tj * 4)      = v0;
        *(float4*)(T + (long)(i0 + i) * NDIM + j0 + 64 + tj * 4) = v1;
    }
}

// ---------------------------------------------------------------------------
// Stage 2: fused LN2 + dual GEMM (po,go) + gate + mask -> output.
// Block: 128-position tile x 64 output cols (grid.y picks half). K=64 one-shot.
// ---------------------------------------------------------------------------
__global__ __launch_bounds__(256, 2)
void k_stage2(const float* __restrict__ wst, const float* __restrict__ mask,
              const float* __restrict__ ln2_w, const float* __restrict__ ln2_b,
              const float* __restrict__ po_w, const float* __restrict__ po_b,
              const float* __restrict__ go_w, const float* __restrict__ go_b,
              float* __restrict__ out)
{
    __shared__ float tT[64][132];    // [ch][pos-local], padded stride
    __shared__ float Wp[64][64];
    __shared__ float Wg[64][64];

    const int tid = threadIdx.x;
    const long pos0 = (long)blockIdx.x * 128;
    const int o0 = blockIdx.y * 64;

    // load t-tile (64 ch x 128 pos) from planes
#pragma unroll
    for (int q = 0; q < 8; ++q) {
        const int u = q*256 + tid, d = u >> 5, p4 = u & 31;
        const float4 v = *(const float4*)(wst + (long)d*NN + pos0 + p4*4);
        *(float4*)&tT[d][p4*4] = v;
    }
    // load weight slabs (cols o0..o0+63, full K=64)
#pragma unroll
    for (int q = 0; q < 4; ++q) {
        const int u = q*256 + tid, k = u >> 4, c4 = u & 15;
        *(float4*)&Wp[k][c4*4] = *(const float4*)(po_w + k*128 + o0 + c4*4);
        *(float4*)&Wg[k][c4*4] = *(const float4*)(go_w + k*128 + o0 + c4*4);
    }
    __syncthreads();

    // LN2 in place on tT (2 threads per row; each element touched by 1 thread)
    {
        const int r = tid >> 1, hf = tid & 1;
        float v[32]; float s = 0.f;
#pragma unroll
        for (int j = 0; j < 32; ++j) { v[j] = tT[hf*32+j][r]; s += v[j]; }
        s += __shfl_xor(s, 1);
        const float mu = s * (1.f/64.f);
        float vs = 0.f;
#pragma unroll
        for (int j = 0; j < 32; ++j) { float d = v[j]-mu; vs += d*d; }
        vs += __shfl_xor(vs, 1);
        const float rstd = rsqrtf(vs*(1.f/64.f) + 1e-5f);
#pragma unroll
        for (int j = 0; j < 32; ++j) {
            const int f = hf*32 + j;
            tT[f][r] = (v[j]-mu)*rstd*ln2_w[f] + ln2_b[f];
        }
    }
    __syncthreads();

    float acc_p[8][4], acc_g[8][4];
#pragma unroll
    for (int a = 0; a < 8; ++a)
#pragma unroll
        for (int b = 0; b < 4; ++b) { acc_p[a][b]=0.f; acc_g[a][b]=0.f; }

    const int ti = tid >> 4, tj = tid & 15;
#pragma unroll
    for (int k = 0; k < 64; ++k) {
        const float4 a0 = *(const float4*)&tT[k][ti*8];
        const float4 a1 = *(const float4*)&tT[k][ti*8+4];
        const float4 pw = *(const float4*)&Wp[k][tj*4];
        const float4 gw = *(const float4*)&Wg[k][tj*4];
        const float av[8] = {a0.x,a0.y,a0.z,a0.w,a1.x,a1.y,a1.z,a1.w};
        const float pv[4] = {pw.x,pw.y,pw.z,pw.w};
        const float gv[4] = {gw.x,gw.y,gw.z,gw.w};
#pragma unroll
        for (int a = 0; a < 8; ++a) {
#pragma unroll
            for (int b = 0; b < 4; ++b) {
                acc_p[a][b] = fmaf(av[a], pv[b], acc_p[a][b]);
                acc_g[a][b] = fmaf(av[a], gv[b], acc_g[a][b]);
            }
        }
    }

    // epilogue: bias, gate, mask, contiguous float4 stores
    float mv[8];
#pragma unroll
    for (int a = 0; a < 8; ++a) mv[a] = mask[pos0 + ti*8 + a];
    float pb4[4], gb4[4];
#pragma unroll
    for (int b = 0; b < 4; ++b) {
        pb4[b] = po_b[o0 + tj*4 + b];
        gb4[b] = go_b[o0 + tj*4 + b];
    }
#pragma unroll
    for (int a = 0; a < 8; ++a) {
        float4 o4;
        o4.x = (acc_p[a][0]+pb4[0]) * sigmoidf_(acc_g[a][0]+gb4[0]) * mv[a];
        o4.y = (acc_p[a][1]+pb4[1]) * sigmoidf_(acc_g[a][1]+gb4[1]) * mv[a];
        o4.z = (acc_p[a][2]+pb4[2]) * sigmoidf_(acc_g[a][2]+gb4[2]) * mv[a];
        o4.w = (acc_p[a][3]+pb4[3]) * sigmoidf_(acc_g[a][3]+gb4[3]) * mv[a];
        *(float4*)(out + (pos0 + ti*8 + a)*128 + o0 + tj*4) = o4;
    }
}

// ---------------------------------------------------------------------------
extern "C" void kernel_launch(void* const* d_in, const int* in_sizes, int n_in,
                              void* d_out, int out_size, void* d_ws, size_t ws_size,
                              hipStream_t stream)
{
    const float* x     = (const float*)d_in[0];
    const float* mask  = (const float*)d_in[1];
    const float* ln1_w = (const float*)d_in[2];
    const float* ln1_b = (const float*)d_in[3];
    const float* pi_w  = (const float*)d_in[4];
    const float* pi_b  = (const float*)d_in[5];
    const float* gi_w  = (const float*)d_in[6];
    const float* gi_b  = (const float*)d_in[7];
    const float* ln2_w = (const float*)d_in[8];
    const float* ln2_b = (const float*)d_in[9];
    const float* po_w  = (const float*)d_in[10];
    const float* po_b  = (const float*)d_in[11];
    const float* go_w  = (const float*)d_in[12];
    const float* go_b  = (const float*)d_in[13];

    float* wsg = (float*)d_ws;                  // 128 g-planes (128 MiB)
    float* wst = wsg + (long)128 * NN;          // 64 t-planes  (64 MiB)

    k_stage1<<<dim3(2048, 2), 256, 0, stream>>>(x, mask, ln1_w, ln1_b,
                                                pi_w, pi_b, gi_w, gi_b, wsg);
    k_einsum<<<dim3(4, 4, 64), 256, 0, stream>>>(wsg, wst);
    k_stage2<<<dim3(2048, 2), 256, 0, stream>>>(wst, mask, ln2_w, ln2_b,
                                                po_w, po_b, go_w, go_b, (float*)d_out);
}

// Round 3
// 497.805 us; speedup vs baseline: 2.3779x; 1.3760x over previous
//
#include <hip/hip_runtime.h>

#define NDIM 512
#define NN   (NDIM * NDIM)

// Workspace layout:
//   bf16 planes 0..127   : g hi, channel c.  c<64: [i][k] = g[i][k][c] (row-strip order)
//                          c>=64: [i][k] = g[k][i][c] (column-strip order, stored directly)
//   bf16 planes 128..255 : g lo, same indexing.                (128 MiB total)
//   fp32 planes (offset 256*NN*2 bytes): t[dd][i][j], 64 planes (64 MiB)

using short8 = __attribute__((ext_vector_type(8))) short;
using f32x4  = __attribute__((ext_vector_type(4))) float;

__device__ __forceinline__ float sigmoidf_(float z) {
    return 1.f / (1.f + __expf(-z));
}
__device__ __forceinline__ unsigned short f2bf(float f) {
    unsigned int u = __float_as_uint(f);
    unsigned int r = (u + 0x7fffu + ((u >> 16) & 1u)) >> 16;
    return (unsigned short)r;
}
__device__ __forceinline__ float bf2f(unsigned short h) {
    return __uint_as_float(((unsigned int)h) << 16);
}

// ---------------------------------------------------------------------------
// Stage 1: fused LN1 + dual GEMM (pi,gi) + gate + mask -> bf16 hi/lo g planes.
// y=0: row-strip blocks, produce channels 0..63 in natural [i][k] layout.
// y=1: column-strip blocks, produce channels 64..127 "transposed" [i][k]
//      layout via contiguous stores (no scatter).
// ---------------------------------------------------------------------------
__global__ __launch_bounds__(256, 2)
void k_stage1(const float* __restrict__ x, const float* __restrict__ mask,
              const float* __restrict__ ln1_w, const float* __restrict__ ln1_b,
              const float* __restrict__ pi_w, const float* __restrict__ pi_b,
              const float* __restrict__ gi_w, const float* __restrict__ gi_b,
              unsigned short* __restrict__ wsg)
{
    __shared__ float hT[128][128];
    __shared__ float Wp[32][64];
    __shared__ float Wg[32][64];

    const int tid = threadIdx.x;
    const int bx = blockIdx.x;
    const int y  = blockIdx.y;
    const int o0 = y * 64;

    long posBase, outBase, stride;
    if (y == 0) {
        posBase = ((long)(bx >> 2)) * 512 + (long)(bx & 3) * 128;
        outBase = posBase; stride = 1;
    } else {
        posBase = ((long)(bx >> 9)) * 128 * 512 + (bx & 511);
        outBase = (long)(bx & 511) * 512 + ((bx >> 9) * 128);
        stride = 512;
    }

    // Prefetch weight slab 0 (overlaps LN phase).
    float4 pnext[2], gnext[2];
#pragma unroll
    for (int q = 0; q < 2; ++q) {
        const int u = q*256 + tid, kk = u >> 4, c4 = u & 15;
        pnext[q] = *(const float4*)(pi_w + kk*128 + o0 + c4*4);
        gnext[q] = *(const float4*)(gi_w + kk*128 + o0 + c4*4);
    }

    // --- LN phase: 2 threads per row, combine via shfl_xor(1) ---
    {
        const int r = tid >> 1, hf = tid & 1;
        const float* xr = x + (posBase + (long)r * stride) * 128 + hf * 64;
        float v[64]; float s = 0.f;
#pragma unroll
        for (int q = 0; q < 16; ++q) {
            float4 t4 = ((const float4*)xr)[q];
            v[4*q+0]=t4.x; v[4*q+1]=t4.y; v[4*q+2]=t4.z; v[4*q+3]=t4.w;
            s += t4.x+t4.y+t4.z+t4.w;
        }
        s += __shfl_xor(s, 1);
        const float mu = s * (1.f/128.f);
        float vs = 0.f;
#pragma unroll
        for (int j = 0; j < 64; ++j) { float d = v[j]-mu; vs += d*d; }
        vs += __shfl_xor(vs, 1);
        const float rstd = rsqrtf(vs*(1.f/128.f) + 1e-5f);
#pragma unroll
        for (int j = 0; j < 64; ++j) {
            const int f = hf*64 + j;
            hT[f][r] = (v[j]-mu)*rstd*ln1_w[f] + ln1_b[f];
        }
    }

    float acc_p[8][4], acc_g[8][4];
#pragma unroll
    for (int a = 0; a < 8; ++a)
#pragma unroll
        for (int b = 0; b < 4; ++b) { acc_p[a][b]=0.f; acc_g[a][b]=0.f; }

    const int ti = tid >> 4, tj = tid & 15;

    for (int kb = 0; kb < 4; ++kb) {
        if (kb) __syncthreads();
#pragma unroll
        for (int q = 0; q < 2; ++q) {
            const int u = q*256 + tid, kk = u >> 4, c4 = u & 15;
            *(float4*)&Wp[kk][c4*4] = pnext[q];
            *(float4*)&Wg[kk][c4*4] = gnext[q];
        }
        __syncthreads();
        if (kb < 3) {
#pragma unroll
            for (int q = 0; q < 2; ++q) {
                const int u = q*256 + tid, kk = u >> 4, c4 = u & 15;
                pnext[q] = *(const float4*)(pi_w + (kb*32+32+kk)*128 + o0 + c4*4);
                gnext[q] = *(const float4*)(gi_w + (kb*32+32+kk)*128 + o0 + c4*4);
            }
        }
        const int kbase = kb*32;
#pragma unroll
        for (int k = 0; k < 32; ++k) {
            const float4 a0 = *(const float4*)&hT[kbase+k][ti*8];
            const float4 a1 = *(const float4*)&hT[kbase+k][ti*8+4];
            const float4 pw = *(const float4*)&Wp[k][tj*4];
            const float4 gw = *(const float4*)&Wg[k][tj*4];
            const float av[8] = {a0.x,a0.y,a0.z,a0.w,a1.x,a1.y,a1.z,a1.w};
            const float pv[4] = {pw.x,pw.y,pw.z,pw.w};
            const float gv[4] = {gw.x,gw.y,gw.z,gw.w};
#pragma unroll
            for (int a = 0; a < 8; ++a) {
#pragma unroll
                for (int b = 0; b < 4; ++b) {
                    acc_p[a][b] = fmaf(av[a], pv[b], acc_p[a][b]);
                    acc_g[a][b] = fmaf(av[a], gv[b], acc_g[a][b]);
                }
            }
        }
    }

    // --- epilogue: bias, gate, mask, bf16 hi/lo split, contiguous stores ---
    float mv[8];
#pragma unroll
    for (int a = 0; a < 8; ++a) mv[a] = mask[posBase + (long)(ti*8 + a) * stride];
#pragma unroll
    for (int b = 0; b < 4; ++b) {
        const int c = o0 + tj*4 + b;
        const float pb = pi_b[c], gb = gi_b[c];
        short8 hv, lv;
#pragma unroll
        for (int a = 0; a < 8; ++a) {
            const float g = (acc_p[a][b] + pb) * sigmoidf_(acc_g[a][b] + gb) * mv[a];
            const unsigned short h = f2bf(g);
            hv[a] = (short)h;
            lv[a] = (short)f2bf(g - bf2f(h));
        }
        unsigned short* hd = wsg + (long)c * NN + outBase + ti*8;
        unsigned short* ld = wsg + (long)(128 + c) * NN + outBase + ti*8;
        *(short8*)hd = hv;
        *(short8*)ld = lv;
    }
}

// ---------------------------------------------------------------------------
// Triangular einsums: 64 channels x NT-GEMM C[i][j] = sum_k P[i][k] Q[j][k],
// bf16 hi/lo split (hh + hl + lh), MFMA 16x16x32.
// Block: 128x128 tile, 4 waves (2x2 of 64x64). BK=64. XOR-swizzled LDS,
// staged via global_load_lds with pre-swizzled source columns.
// ---------------------------------------------------------------------------
__global__ __launch_bounds__(256, 2)
void k_einsum(const unsigned short* __restrict__ wsg, float* __restrict__ wst)
{
    // XCD-chunked swizzle: each XCD owns 8 consecutive channels.
    const int bid = blockIdx.x;                 // 0..1023
    const int nb  = (bid & 7) * 128 + (bid >> 3);
    const int ch  = nb >> 4;
    const int bi  = (nb >> 2) & 3, bj = nb & 3;
    const int pch = (ch < 32) ? ch : ch + 32;

    const unsigned short* __restrict__ PH = wsg + (long)pch * NN;
    const unsigned short* __restrict__ PL = wsg + (long)(128 + pch) * NN;
    const unsigned short* __restrict__ QH = wsg + (long)(pch + 32) * NN;
    const unsigned short* __restrict__ QL = wsg + (long)(128 + pch + 32) * NN;
    float* __restrict__ T = wst + (long)ch * NN;

    __shared__ unsigned short smem[4 * 8192];   // 64 KiB: Ah, Al, Bh, Bl tiles [128][64]

    const int tid = threadIdx.x;
    const int w = tid >> 6, l = tid & 63;

    // Per-lane staging source element offsets (pre-swizzled column),
    // for the 4 calls this wave makes per tile.
    int ebase[4];
#pragma unroll
    for (int j = 0; j < 4; ++j) {
        const int ci  = w * 256 + j * 64 + l;   // chunk index in tile (16B units)
        const int row = ci >> 3, cs = ci & 7;
        ebase[j] = row * 512 + ((cs ^ (row & 7)) << 3);   // ushort units
    }
    const int aOff = bi * 128 * 512;   // ushort units
    const int bOff = bj * 128 * 512;

    f32x4 acc[4][4];
#pragma unroll
    for (int m = 0; m < 4; ++m)
#pragma unroll
        for (int n = 0; n < 4; ++n) acc[m][n] = (f32x4){0.f, 0.f, 0.f, 0.f};

    const int mrow = (w & 1) * 64;   // wave's row quadrant
    const int ncol = (w >> 1) * 64;  // wave's col quadrant

    for (int step = 0; step < 8; ++step) {
        __syncthreads();             // prior step's LDS reads complete
        const int kOff = step * 64;  // ushort units
#pragma unroll
        for (int j = 0; j < 4; ++j) {
            char* dst = (char*)smem + (w * 256 + j * 64) * 16;
            const unsigned short* sa_h = PH + aOff + ebase[j] + kOff;
            const unsigned short* sa_l = PL + aOff + ebase[j] + kOff;
            const unsigned short* sb_h = QH + bOff + ebase[j] + kOff;
            const unsigned short* sb_l = QL + bOff + ebase[j] + kOff;
            __builtin_amdgcn_global_load_lds((const __attribute__((address_space(1))) void*)sa_h,
                (__attribute__((address_space(3))) void*)(dst), 16, 0, 0);
            __builtin_amdgcn_global_load_lds((const __attribute__((address_space(1))) void*)sa_l,
                (__attribute__((address_space(3))) void*)(dst + 16384), 16, 0, 0);
            __builtin_amdgcn_global_load_lds((const __attribute__((address_space(1))) void*)sb_h,
                (__attribute__((address_space(3))) void*)(dst + 32768), 16, 0, 0);
            __builtin_amdgcn_global_load_lds((const __attribute__((address_space(1))) void*)sb_l,
                (__attribute__((address_space(3))) void*)(dst + 49152), 16, 0, 0);
        }
        __syncthreads();             // vmcnt(0) drained by barrier -> LDS valid

#pragma unroll
        for (int ks = 0; ks < 2; ++ks) {
            short8 ah[4], al[4], bh[4], bl[4];
#pragma unroll
            for (int m = 0; m < 4; ++m) {
                const int r = mrow + m * 16 + (l & 15);
                const int off = r * 128 + ((((ks << 2) + (l >> 4)) ^ (r & 7)) << 4);
                ah[m] = *(const short8*)((const char*)smem + off);
                al[m] = *(const short8*)((const char*)smem + 16384 + off);
            }
#pragma unroll
            for (int n = 0; n < 4; ++n) {
                const int r = ncol + n * 16 + (l & 15);
                const int off = r * 128 + ((((ks << 2) + (l >> 4)) ^ (r & 7)) << 4);
                bh[n] = *(const short8*)((const char*)smem + 32768 + off);
                bl[n] = *(const short8*)((const char*)smem + 49152 + off);
            }
#pragma unroll
            for (int m = 0; m < 4; ++m) {
#pragma unroll
                for (int n = 0; n < 4; ++n) {
                    acc[m][n] = __builtin_amdgcn_mfma_f32_16x16x32_bf16(ah[m], bh[n], acc[m][n], 0, 0, 0);
                    acc[m][n] = __builtin_amdgcn_mfma_f32_16x16x32_bf16(ah[m], bl[n], acc[m][n], 0, 0, 0);
                    acc[m][n] = __builtin_amdgcn_mfma_f32_16x16x32_bf16(al[m], bh[n], acc[m][n], 0, 0, 0);
                }
            }
        }
    }

    // Epilogue: C/D layout col = lane&15, row = (lane>>4)*4 + reg (m89-verified).
    const int rbase = bi * 128 + mrow;
    const int cbase = bj * 128 + ncol;
#pragma unroll
    for (int m = 0; m < 4; ++m) {
#pragma unroll
        for (int n = 0; n < 4; ++n) {
#pragma unroll
            for (int r = 0; r < 4; ++r) {
                const int row = rbase + m * 16 + (l >> 4) * 4 + r;
                const int col = cbase + n * 16 + (l & 15);
                T[(long)row * NDIM + col] = acc[m][n][r];
            }
        }
    }
}

// ---------------------------------------------------------------------------
// Stage 2: fused LN2 + dual GEMM (po,go) + gate + mask -> output.
// ---------------------------------------------------------------------------
__global__ __launch_bounds__(256, 2)
void k_stage2(const float* __restrict__ wst, const float* __restrict__ mask,
              const float* __restrict__ ln2_w, const float* __restrict__ ln2_b,
              const float* __restrict__ po_w, const float* __restrict__ po_b,
              const float* __restrict__ go_w, const float* __restrict__ go_b,
              float* __restrict__ out)
{
    __shared__ float tT[64][132];
    __shared__ float Wp[64][64];
    __shared__ float Wg[64][64];

    const int tid = threadIdx.x;
    const long pos0 = (long)blockIdx.x * 128;
    const int o0 = blockIdx.y * 64;

#pragma unroll
    for (int q = 0; q < 8; ++q) {
        const int u = q*256 + tid, d = u >> 5, p4 = u & 31;
        const float4 v = *(const float4*)(wst + (long)d*NN + pos0 + p4*4);
        *(float4*)&tT[d][p4*4] = v;
    }
#pragma unroll
    for (int q = 0; q < 4; ++q) {
        const int u = q*256 + tid, k = u >> 4, c4 = u & 15;
        *(float4*)&Wp[k][c4*4] = *(const float4*)(po_w + k*128 + o0 + c4*4);
        *(float4*)&Wg[k][c4*4] = *(const float4*)(go_w + k*128 + o0 + c4*4);
    }
    __syncthreads();

    {
        const int r = tid >> 1, hf = tid & 1;
        float v[32]; float s = 0.f;
#pragma unroll
        for (int j = 0; j < 32; ++j) { v[j] = tT[hf*32+j][r]; s += v[j]; }
        s += __shfl_xor(s, 1);
        const float mu = s * (1.f/64.f);
        float vs = 0.f;
#pragma unroll
        for (int j = 0; j < 32; ++j) { float d = v[j]-mu; vs += d*d; }
        vs += __shfl_xor(vs, 1);
        const float rstd = rsqrtf(vs*(1.f/64.f) + 1e-5f);
#pragma unroll
        for (int j = 0; j < 32; ++j) {
            const int f = hf*32 + j;
            tT[f][r] = (v[j]-mu)*rstd*ln2_w[f] + ln2_b[f];
        }
    }
    __syncthreads();

    float acc_p[8][4], acc_g[8][4];
#pragma unroll
    for (int a = 0; a < 8; ++a)
#pragma unroll
        for (int b = 0; b < 4; ++b) { acc_p[a][b]=0.f; acc_g[a][b]=0.f; }

    const int ti = tid >> 4, tj = tid & 15;
#pragma unroll
    for (int k = 0; k < 64; ++k) {
        const float4 a0 = *(const float4*)&tT[k][ti*8];
        const float4 a1 = *(const float4*)&tT[k][ti*8+4];
        const float4 pw = *(const float4*)&Wp[k][tj*4];
        const float4 gw = *(const float4*)&Wg[k][tj*4];
        const float av[8] = {a0.x,a0.y,a0.z,a0.w,a1.x,a1.y,a1.z,a1.w};
        const float pv[4] = {pw.x,pw.y,pw.z,pw.w};
        const float gv[4] = {gw.x,gw.y,gw.z,gw.w};
#pragma unroll
        for (int a = 0; a < 8; ++a) {
#pragma unroll
            for (int b = 0; b < 4; ++b) {
                acc_p[a][b] = fmaf(av[a], pv[b], acc_p[a][b]);
                acc_g[a][b] = fmaf(av[a], gv[b], acc_g[a][b]);
            }
        }
    }

    float mv[8];
#pragma unroll
    for (int a = 0; a < 8; ++a) mv[a] = mask[pos0 + ti*8 + a];
    float pb4[4], gb4[4];
#pragma unroll
    for (int b = 0; b < 4; ++b) {
        pb4[b] = po_b[o0 + tj*4 + b];
        gb4[b] = go_b[o0 + tj*4 + b];
    }
#pragma unroll
    for (int a = 0; a < 8; ++a) {
        float4 o4;
        o4.x = (acc_p[a][0]+pb4[0]) * sigmoidf_(acc_g[a][0]+gb4[0]) * mv[a];
        o4.y = (acc_p[a][1]+pb4[1]) * sigmoidf_(acc_g[a][1]+gb4[1]) * mv[a];
        o4.z = (acc_p[a][2]+pb4[2]) * sigmoidf_(acc_g[a][2]+gb4[2]) * mv[a];
        o4.w = (acc_p[a][3]+pb4[3]) * sigmoidf_(acc_g[a][3]+gb4[3]) * mv[a];
        *(float4*)(out + (pos0 + ti*8 + a)*128 + o0 + tj*4) = o4;
    }
}

// ---------------------------------------------------------------------------
extern "C" void kernel_launch(void* const* d_in, const int* in_sizes, int n_in,
                              void* d_out, int out_size, void* d_ws, size_t ws_size,
                              hipStream_t stream)
{
    const float* x     = (const float*)d_in[0];
    const float* mask  = (const float*)d_in[1];
    const float* ln1_w = (const float*)d_in[2];
    const float* ln1_b = (const float*)d_in[3];
    const float* pi_w  = (const float*)d_in[4];
    const float* pi_b  = (const float*)d_in[5];
    const float* gi_w  = (const float*)d_in[6];
    const float* gi_b  = (const float*)d_in[7];
    const float* ln2_w = (const float*)d_in[8];
    const float* ln2_b = (const float*)d_in[9];
    const float* po_w  = (const float*)d_in[10];
    const float* po_b  = (const float*)d_in[11];
    const float* go_w  = (const float*)d_in[12];
    const float* go_b  = (const float*)d_in[13];

    unsigned short* wsg = (unsigned short*)d_ws;            // 256 bf16 planes (128 MiB)
    float* wst = (float*)((char*)d_ws + (long)256 * NN * 2); // 64 fp32 planes (64 MiB)

    k_stage1<<<dim3(2048, 2), 256, 0, stream>>>(x, mask, ln1_w, ln1_b,
                                                pi_w, pi_b, gi_w, gi_b, wsg);
    k_einsum<<<1024, 256, 0, stream>>>(wsg, wst);
    k_stage2<<<dim3(2048, 2), 256, 0, stream>>>(wst, mask, ln2_w, ln2_b,
                                                po_w, po_b, go_w, go_b, (float*)d_out);
}

// Round 4
// 488.130 us; speedup vs baseline: 2.4250x; 1.0198x over previous
//
#include <hip/hip_runtime.h>

#define NDIM 512
#define NN   (NDIM * NDIM)

// Workspace layout:
//   bf16 planes 0..127   : g hi, channel c.  c<64: [i][k]=g[i][k][c]; c>=64: [i][k]=g[k][i][c]
//   bf16 planes 128..255 : g lo, same indexing.              (128 MiB)
//   fp32 planes @ 256*NN*2 bytes: t[dd][i][j], 64 planes      (64 MiB)
// Transient:
//   Wt1 (bf16 hi/lo, 128 KiB) lives at wst start until einsum overwrites it.
//   Wt2 (bf16 hi/lo, 64 KiB) written into wsg start AFTER einsum reads g.

using short8 = __attribute__((ext_vector_type(8))) short;
using s16x4  = __attribute__((ext_vector_type(4))) short;
using f32x4  = __attribute__((ext_vector_type(4))) float;
typedef unsigned long long ull;

__device__ __forceinline__ float sigmoidf_(float z) { return 1.f / (1.f + __expf(-z)); }
__device__ __forceinline__ unsigned short f2bf(float f) {
    unsigned int u = __float_as_uint(f);
    return (unsigned short)((u + 0x7fffu + ((u >> 16) & 1u)) >> 16);
}
__device__ __forceinline__ float bf2f(unsigned short h) {
    return __uint_as_float(((unsigned int)h) << 16);
}

// ---------------------------------------------------------------------------
// Weight prep: W^T bf16 hi/lo, rows interleaved: row 16q+s -> s<8: P ch 8q+s,
// s>=8: G ch 8q+s-8.  dst layout: hi[(h*128+row)*K + k], lo at dst+256*K.
// ---------------------------------------------------------------------------
__global__ void k_prep(const float* __restrict__ Wp, const float* __restrict__ Wg,
                       int K, unsigned short* __restrict__ dst)
{
    const int h = blockIdx.x, t = threadIdx.x;
    const int row = t >> 1, kh = t & 1;
    const int q = row >> 4, s = row & 15;
    const float* W = (s < 8) ? Wp : Wg;
    const int o = h * 64 + q * 8 + (s & 7);
    const int kHalf = K >> 1;
    for (int k = kh * kHalf; k < (kh + 1) * kHalf; ++k) {
        const float v = W[k * 128 + o];
        const unsigned short hi = f2bf(v);
        const unsigned short lo = f2bf(v - bf2f(hi));
        dst[(h * 128 + row) * K + k] = hi;
        dst[256 * K + (h * 128 + row) * K + k] = lo;
    }
}

// ---------------------------------------------------------------------------
// Stage 1: LN1 + dual GEMM (pi,gi interleaved in Wt1) via MFMA hi/lo split,
// gate via shfl_xor(8), g -> bf16 hi/lo planes with coalesced 256B stores.
// ---------------------------------------------------------------------------
__global__ __launch_bounds__(256, 2)
void k_stage1(const float* __restrict__ x, const float* __restrict__ mask,
              const float* __restrict__ ln1_w, const float* __restrict__ ln1_b,
              const float* __restrict__ pi_b_, const float* __restrict__ gi_b_,
              const unsigned short* __restrict__ wt1,
              unsigned short* __restrict__ wsg)
{
    __shared__ char sbuf[65536];   // A hi [0,32K), A lo [32K,64K); later G hi [0,16K), G lo [16K,32K)
    __shared__ float Ms[128];

    const int tid = threadIdx.x;
    const int bx = blockIdx.x;
    const int y  = blockIdx.y;
    const int o0 = y * 64;

    long posBase, outBase; int stride;
    if (y == 0) {
        posBase = ((long)(bx >> 2)) * 512 + (long)(bx & 3) * 128;
        outBase = posBase; stride = 1;
    } else {
        posBase = ((long)(bx >> 9)) * 65536 + (bx & 511);
        outBase = (long)(bx & 511) * 512 + ((bx >> 9) * 128);
        stride = 512;
    }

    // --- LN + bf16 hi/lo split into swizzled A tiles ---
    {
        const int r = tid >> 1, hf = tid & 1;
        const float* xr = x + (posBase + (long)r * stride) * 128 + hf * 64;
        float v[64]; float s = 0.f;
#pragma unroll
        for (int q = 0; q < 16; ++q) {
            float4 t4 = ((const float4*)xr)[q];
            v[4*q+0]=t4.x; v[4*q+1]=t4.y; v[4*q+2]=t4.z; v[4*q+3]=t4.w;
            s += t4.x+t4.y+t4.z+t4.w;
        }
        s += __shfl_xor(s, 1);
        const float mu = s * (1.f/128.f);
        float vs = 0.f;
#pragma unroll
        for (int jz = 0; jz < 64; ++jz) { float d = v[jz]-mu; vs += d*d; }
        vs += __shfl_xor(vs, 1);
        const float rstd = rsqrtf(vs*(1.f/128.f) + 1e-5f);
        if (hf == 0) Ms[r] = mask[posBase + (long)r * stride];
#pragma unroll
        for (int jj = 0; jj < 8; ++jj) {
            short8 hv, lv;
#pragma unroll
            for (int e = 0; e < 8; ++e) {
                const int f = hf*64 + jj*8 + e;
                const float ln = (v[jj*8+e]-mu)*rstd*ln1_w[f] + ln1_b[f];
                const unsigned short hi = f2bf(ln);
                hv[e] = (short)hi;
                lv[e] = (short)f2bf(ln - bf2f(hi));
            }
            const int col = (hf*128 + jj*16) ^ ((r & 15) << 4);
            *(short8*)(sbuf + r*256 + col) = hv;
            *(short8*)(sbuf + 32768 + r*256 + col) = lv;
        }
    }
    __syncthreads();

    const int w = tid >> 6, l = tid & 63;
    const int mrow = (w & 1) * 64, ncol = (w >> 1) * 64;

    f32x4 acc[4][4];
#pragma unroll
    for (int m = 0; m < 4; ++m)
#pragma unroll
        for (int n = 0; n < 4; ++n) acc[m][n] = (f32x4){0.f,0.f,0.f,0.f};

#pragma unroll
    for (int step = 0; step < 4; ++step) {
        short8 ah[4], al[4], bh[4], bl[4];
#pragma unroll
        for (int n = 0; n < 4; ++n) {
            const int row = y*128 + ncol + n*16 + (l & 15);
            const int idx = row*128 + step*32 + (l >> 4)*8;
            bh[n] = *(const short8*)(wt1 + idx);
            bl[n] = *(const short8*)(wt1 + 32768 + idx);
        }
#pragma unroll
        for (int m = 0; m < 4; ++m) {
            const int pos = mrow + m*16 + (l & 15);
            const int col = (step*64 + (l >> 4)*16) ^ ((pos & 15) << 4);
            ah[m] = *(const short8*)(sbuf + pos*256 + col);
            al[m] = *(const short8*)(sbuf + 32768 + pos*256 + col);
        }
#pragma unroll
        for (int m = 0; m < 4; ++m) {
#pragma unroll
            for (int n = 0; n < 4; ++n) {
                acc[m][n] = __builtin_amdgcn_mfma_f32_16x16x32_bf16(ah[m], bh[n], acc[m][n], 0, 0, 0);
                acc[m][n] = __builtin_amdgcn_mfma_f32_16x16x32_bf16(ah[m], bl[n], acc[m][n], 0, 0, 0);
                acc[m][n] = __builtin_amdgcn_mfma_f32_16x16x32_bf16(al[m], bh[n], acc[m][n], 0, 0, 0);
            }
        }
    }
    __syncthreads();   // all A reads done; sbuf becomes G

    // --- gate (pi: cols 0..7, gi: cols 8..15 of each fragment) + G write ---
    const int j = l & 15;
#pragma unroll
    for (int m = 0; m < 4; ++m) {
#pragma unroll
        for (int n = 0; n < 4; ++n) {
            const f32x4 a = acc[m][n];
            float pr[4];
#pragma unroll
            for (int e = 0; e < 4; ++e) pr[e] = __shfl_xor(a[e], 8);
            if (j < 8) {
                const int cl = (w >> 1)*32 + n*8 + j;
                const float pb = pi_b_[o0 + cl], gb = gi_b_[o0 + cl];
                const int p0 = mrow + m*16 + (l >> 4)*4;
                s16x4 hv, lv;
#pragma unroll
                for (int e = 0; e < 4; ++e) {
                    const float g = (a[e] + pb) * sigmoidf_(pr[e] + gb) * Ms[p0 + e];
                    const unsigned short hi = f2bf(g);
                    hv[e] = (short)hi;
                    lv[e] = (short)f2bf(g - bf2f(hi));
                }
                const int byte = cl*256 + ((p0*2) ^ ((cl & 7) << 3));
                *(s16x4*)(sbuf + byte) = hv;
                *(s16x4*)(sbuf + 16384 + byte) = lv;
            }
        }
    }
    __syncthreads();

    // --- cooperative plane stores: 256B contiguous per plane ---
    {
        const int c = tid >> 2, qp = tid & 3;
#pragma unroll
        for (int part = 0; part < 2; ++part) {
            const char* basep = sbuf + part*16384 + c*256;
            unsigned short* dst = wsg + (long)(o0 + c + part*128) * NN + outBase + qp*32;
#pragma unroll
            for (int i = 0; i < 4; ++i) {
                const int q0 = qp*8 + 2*i;
                union { ull u[2]; short8 s8; } cv;
                cv.u[0] = *(const ull*)(basep + ((q0*8)     ^ ((c & 7) << 3)));
                cv.u[1] = *(const ull*)(basep + ((q0*8 + 8) ^ ((c & 7) << 3)));
                *(short8*)(dst + i*8) = cv.s8;
            }
        }
    }
}

// ---------------------------------------------------------------------------
// Triangular einsums (unchanged from round 3): 64 NT-GEMMs, bf16 hi/lo MFMA.
// ---------------------------------------------------------------------------
__global__ __launch_bounds__(256, 2)
void k_einsum(const unsigned short* __restrict__ wsg, float* __restrict__ wst)
{
    const int bid = blockIdx.x;
    const int nb  = (bid & 7) * 128 + (bid >> 3);
    const int ch  = nb >> 4;
    const int bi  = (nb >> 2) & 3, bj = nb & 3;
    const int pch = (ch < 32) ? ch : ch + 32;

    const unsigned short* __restrict__ PH = wsg + (long)pch * NN;
    const unsigned short* __restrict__ PL = wsg + (long)(128 + pch) * NN;
    const unsigned short* __restrict__ QH = wsg + (long)(pch + 32) * NN;
    const unsigned short* __restrict__ QL = wsg + (long)(128 + pch + 32) * NN;
    float* __restrict__ T = wst + (long)ch * NN;

    __shared__ unsigned short smem[4 * 8192];

    const int tid = threadIdx.x;
    const int w = tid >> 6, l = tid & 63;

    int ebase[4];
#pragma unroll
    for (int j = 0; j < 4; ++j) {
        const int ci  = w * 256 + j * 64 + l;
        const int row = ci >> 3, cs = ci & 7;
        ebase[j] = row * 512 + ((cs ^ (row & 7)) << 3);
    }
    const int aOff = bi * 128 * 512;
    const int bOff = bj * 128 * 512;

    f32x4 acc[4][4];
#pragma unroll
    for (int m = 0; m < 4; ++m)
#pragma unroll
        for (int n = 0; n < 4; ++n) acc[m][n] = (f32x4){0.f, 0.f, 0.f, 0.f};

    const int mrow = (w & 1) * 64;
    const int ncol = (w >> 1) * 64;

    for (int step = 0; step < 8; ++step) {
        __syncthreads();
        const int kOff = step * 64;
#pragma unroll
        for (int j = 0; j < 4; ++j) {
            char* dst = (char*)smem + (w * 256 + j * 64) * 16;
            const unsigned short* sa_h = PH + aOff + ebase[j] + kOff;
            const unsigned short* sa_l = PL + aOff + ebase[j] + kOff;
            const unsigned short* sb_h = QH + bOff + ebase[j] + kOff;
            const unsigned short* sb_l = QL + bOff + ebase[j] + kOff;
            __builtin_amdgcn_global_load_lds((const __attribute__((address_space(1))) void*)sa_h,
                (__attribute__((address_space(3))) void*)(dst), 16, 0, 0);
            __builtin_amdgcn_global_load_lds((const __attribute__((address_space(1))) void*)sa_l,
                (__attribute__((address_space(3))) void*)(dst + 16384), 16, 0, 0);
            __builtin_amdgcn_global_load_lds((const __attribute__((address_space(1))) void*)sb_h,
                (__attribute__((address_space(3))) void*)(dst + 32768), 16, 0, 0);
            __builtin_amdgcn_global_load_lds((const __attribute__((address_space(1))) void*)sb_l,
                (__attribute__((address_space(3))) void*)(dst + 49152), 16, 0, 0);
        }
        __syncthreads();

#pragma unroll
        for (int ks = 0; ks < 2; ++ks) {
            short8 ah[4], al[4], bh[4], bl[4];
#pragma unroll
            for (int m = 0; m < 4; ++m) {
                const int r = mrow + m * 16 + (l & 15);
                const int off = r * 128 + ((((ks << 2) + (l >> 4)) ^ (r & 7)) << 4);
                ah[m] = *(const short8*)((const char*)smem + off);
                al[m] = *(const short8*)((const char*)smem + 16384 + off);
            }
#pragma unroll
            for (int n = 0; n < 4; ++n) {
                const int r = ncol + n * 16 + (l & 15);
                const int off = r * 128 + ((((ks << 2) + (l >> 4)) ^ (r & 7)) << 4);
                bh[n] = *(const short8*)((const char*)smem + 32768 + off);
                bl[n] = *(const short8*)((const char*)smem + 49152 + off);
            }
#pragma unroll
            for (int m = 0; m < 4; ++m) {
#pragma unroll
                for (int n = 0; n < 4; ++n) {
                    acc[m][n] = __builtin_amdgcn_mfma_f32_16x16x32_bf16(ah[m], bh[n], acc[m][n], 0, 0, 0);
                    acc[m][n] = __builtin_amdgcn_mfma_f32_16x16x32_bf16(ah[m], bl[n], acc[m][n], 0, 0, 0);
                    acc[m][n] = __builtin_amdgcn_mfma_f32_16x16x32_bf16(al[m], bh[n], acc[m][n], 0, 0, 0);
                }
            }
        }
    }

    const int rbase = bi * 128 + mrow;
    const int cbase = bj * 128 + ncol;
#pragma unroll
    for (int m = 0; m < 4; ++m) {
#pragma unroll
        for (int n = 0; n < 4; ++n) {
#pragma unroll
            for (int r = 0; r < 4; ++r) {
                const int row = rbase + m * 16 + (l >> 4) * 4 + r;
                const int col = cbase + n * 16 + (l & 15);
                T[(long)row * NDIM + col] = acc[m][n][r];
            }
        }
    }
}

// ---------------------------------------------------------------------------
// Stage 2: gather t planes, LN2, dual GEMM (po,go) via MFMA hi/lo, gate, mask.
// ---------------------------------------------------------------------------
__global__ __launch_bounds__(256, 2)
void k_stage2(const float* __restrict__ wst, const float* __restrict__ mask,
              const float* __restrict__ ln2_w, const float* __restrict__ ln2_b,
              const float* __restrict__ po_b_, const float* __restrict__ go_b_,
              const unsigned short* __restrict__ wt2,
              float* __restrict__ out)
{
    __shared__ float tP[128][65];   // t gather; later reused as O[pos][ch]
    __shared__ char abuf[32768];    // A hi [0,16K), A lo [16K,32K)
    __shared__ float Ms[128];

    const int tid = threadIdx.x;
    const long pos0 = (long)blockIdx.x * 128;
    const int y = blockIdx.y;
    const int o0 = y * 64;

    // gather 64 t planes into [pos][ch]
#pragma unroll
    for (int q = 0; q < 8; ++q) {
        const int u = q*256 + tid, d = u >> 5, p4 = u & 31;
        const float4 v = *(const float4*)(wst + (long)d * NN + pos0 + p4*4);
        tP[p4*4+0][d] = v.x; tP[p4*4+1][d] = v.y;
        tP[p4*4+2][d] = v.z; tP[p4*4+3][d] = v.w;
    }
    if (tid < 128) Ms[tid] = mask[pos0 + tid];
    __syncthreads();

    // LN2 rows -> swizzled bf16 hi/lo A tile
    {
        const int r = tid >> 1, hf = tid & 1;
        float v[32]; float s = 0.f;
#pragma unroll
        for (int jz = 0; jz < 32; ++jz) { v[jz] = tP[r][hf*32+jz]; s += v[jz]; }
        s += __shfl_xor(s, 1);
        const float mu = s * (1.f/64.f);
        float vs = 0.f;
#pragma unroll
        for (int jz = 0; jz < 32; ++jz) { float d = v[jz]-mu; vs += d*d; }
        vs += __shfl_xor(vs, 1);
        const float rstd = rsqrtf(vs*(1.f/64.f) + 1e-5f);
#pragma unroll
        for (int jj = 0; jj < 4; ++jj) {
            short8 hv, lv;
#pragma unroll
            for (int e = 0; e < 8; ++e) {
                const int f = hf*32 + jj*8 + e;
                const float ln = (v[jj*8+e]-mu)*rstd*ln2_w[f] + ln2_b[f];
                const unsigned short hi = f2bf(ln);
                hv[e] = (short)hi;
                lv[e] = (short)f2bf(ln - bf2f(hi));
            }
            const int col = (hf*64 + jj*16) ^ ((r & 7) << 4);
            *(short8*)(abuf + r*128 + col) = hv;
            *(short8*)(abuf + 16384 + r*128 + col) = lv;
        }
    }
    __syncthreads();

    const int w = tid >> 6, l = tid & 63;
    const int mrow = (w & 1) * 64, ncol = (w >> 1) * 64;

    f32x4 acc[4][4];
#pragma unroll
    for (int m = 0; m < 4; ++m)
#pragma unroll
        for (int n = 0; n < 4; ++n) acc[m][n] = (f32x4){0.f,0.f,0.f,0.f};

#pragma unroll
    for (int step = 0; step < 2; ++step) {
        short8 ah[4], al[4], bh[4], bl[4];
#pragma unroll
        for (int n = 0; n < 4; ++n) {
            const int row = y*128 + ncol + n*16 + (l & 15);
            const int idx = row*64 + step*32 + (l >> 4)*8;
            bh[n] = *(const short8*)(wt2 + idx);
            bl[n] = *(const short8*)(wt2 + 16384 + idx);
        }
#pragma unroll
        for (int m = 0; m < 4; ++m) {
            const int pos = mrow + m*16 + (l & 15);
            const int col = (step*64 + (l >> 4)*16) ^ ((pos & 7) << 4);
            ah[m] = *(const short8*)(abuf + pos*128 + col);
            al[m] = *(const short8*)(abuf + 16384 + pos*128 + col);
        }
#pragma unroll
        for (int m = 0; m < 4; ++m) {
#pragma unroll
            for (int n = 0; n < 4; ++n) {
                acc[m][n] = __builtin_amdgcn_mfma_f32_16x16x32_bf16(ah[m], bh[n], acc[m][n], 0, 0, 0);
                acc[m][n] = __builtin_amdgcn_mfma_f32_16x16x32_bf16(ah[m], bl[n], acc[m][n], 0, 0, 0);
                acc[m][n] = __builtin_amdgcn_mfma_f32_16x16x32_bf16(al[m], bh[n], acc[m][n], 0, 0, 0);
            }
        }
    }

    // gate + O[pos][ch] (tP dead after LN barrier; abuf untouched)
    const int j = l & 15;
#pragma unroll
    for (int m = 0; m < 4; ++m) {
#pragma unroll
        for (int n = 0; n < 4; ++n) {
            const f32x4 a = acc[m][n];
            float pr[4];
#pragma unroll
            for (int e = 0; e < 4; ++e) pr[e] = __shfl_xor(a[e], 8);
            if (j < 8) {
                const int cl = (w >> 1)*32 + n*8 + j;
                const float pb = po_b_[o0 + cl], gb = go_b_[o0 + cl];
                const int p0 = mrow + m*16 + (l >> 4)*4;
#pragma unroll
                for (int e = 0; e < 4; ++e)
                    tP[p0 + e][cl] = (a[e] + pb) * sigmoidf_(pr[e] + gb) * Ms[p0 + e];
            }
        }
    }
    __syncthreads();

    // cooperative output stores: 128B contiguous per thread, 256B per pair
    {
        const int r2 = tid >> 1, h2 = tid & 1;
        float* op = out + (pos0 + r2)*128 + o0 + h2*32;
#pragma unroll
        for (int i = 0; i < 8; ++i) {
            float4 v;
            v.x = tP[r2][h2*32 + i*4 + 0];
            v.y = tP[r2][h2*32 + i*4 + 1];
            v.z = tP[r2][h2*32 + i*4 + 2];
            v.w = tP[r2][h2*32 + i*4 + 3];
            *(float4*)(op + i*4) = v;
        }
    }
}

// ---------------------------------------------------------------------------
extern "C" void kernel_launch(void* const* d_in, const int* in_sizes, int n_in,
                              void* d_out, int out_size, void* d_ws, size_t ws_size,
                              hipStream_t stream)
{
    const float* x     = (const float*)d_in[0];
    const float* mask  = (const float*)d_in[1];
    const float* ln1_w = (const float*)d_in[2];
    const float* ln1_b = (const float*)d_in[3];
    const float* pi_w  = (const float*)d_in[4];
    const float* pi_b  = (const float*)d_in[5];
    const float* gi_w  = (const float*)d_in[6];
    const float* gi_b  = (const float*)d_in[7];
    const float* ln2_w = (const float*)d_in[8];
    const float* ln2_b = (const float*)d_in[9];
    const float* po_w  = (const float*)d_in[10];
    const float* po_b  = (const float*)d_in[11];
    const float* go_w  = (const float*)d_in[12];
    const float* go_b  = (const float*)d_in[13];

    unsigned short* wsg = (unsigned short*)d_ws;              // 256 bf16 planes
    float* wst = (float*)((char*)d_ws + (long)256 * NN * 2);  // 64 fp32 planes
    unsigned short* wt1 = (unsigned short*)wst;               // transient (pre-einsum)
    unsigned short* wt2 = wsg;                                // transient (post-einsum)

    k_prep<<<2, 256, 0, stream>>>(pi_w, gi_w, 128, wt1);
    k_stage1<<<dim3(2048, 2), 256, 0, stream>>>(x, mask, ln1_w, ln1_b,
                                                pi_b, gi_b, wt1, wsg);
    k_einsum<<<1024, 256, 0, stream>>>(wsg, wst);
    k_prep<<<2, 256, 0, stream>>>(po_w, go_w, 64, wt2);
    k_stage2<<<dim3(2048, 2), 256, 0, stream>>>(wst, mask, ln2_w, ln2_b,
                                                po_b, go_b, wt2, (float*)d_out);
}

// Round 6
// 365.687 us; speedup vs baseline: 3.2370x; 1.3348x over previous
//
#include <hip/hip_runtime.h>

#define NDIM 512
#define NN   (NDIM * NDIM)

// Workspace layout:
//   bf16 planes 0..127   : g hi, channel c.  c<64: [i][k]=g[i][k][c]; c>=64: [i][k]=g[k][i][c]
//   bf16 planes 128..255 : g lo, same indexing.              (128 MiB)
//   fp32 planes @ 256*NN*2 bytes: t[dd][i][j], 64 planes      (64 MiB)
// Transient: Wt1 (hi/lo bf16 of pi/gi^T) at wst start until einsum overwrites;
//            Wt2 (hi/lo bf16 of po/go^T) at wsg start after einsum consumes g.

using short8 = __attribute__((ext_vector_type(8))) short;
using f32x4  = __attribute__((ext_vector_type(4))) float;
typedef unsigned int uint32;

__device__ __forceinline__ float sigmoidf_(float z) { return 1.f / (1.f + __expf(-z)); }
__device__ __forceinline__ unsigned short f2bf(float f) {
    unsigned int u = __float_as_uint(f);
    return (unsigned short)((u + 0x7fffu + ((u >> 16) & 1u)) >> 16);
}
__device__ __forceinline__ float bf2f(unsigned short h) {
    return __uint_as_float(((unsigned int)h) << 16);
}

// ---------------------------------------------------------------------------
// Weight prep (parallel, coalesced reads): W^T bf16 hi/lo, rows interleaved
// in 16-row groups: row 16q+s -> s<8: P ch 8q+s; s>=8: G ch 8q+s-8.
// dst: hi[(h*128+row)*K + k], lo at dst + 256*K.  Grid: K/2 blocks x 256.
// ---------------------------------------------------------------------------
__global__ void k_prep(const float* __restrict__ Wp, const float* __restrict__ Wg,
                       int K, unsigned short* __restrict__ dst)
{
    const int idx = blockIdx.x * 256 + threadIdx.x;   // 0 .. K*128-1
    const int k = idx >> 7, o = idx & 127;
    const int h = o >> 6, cl = o & 63;
    const int q = cl >> 3, s7 = cl & 7;
    const float vp = Wp[k * 128 + o];
    const float vg = Wg[k * 128 + o];
    const int rowp = (q << 4) + s7;
    const int rowg = (q << 4) + 8 + s7;
    unsigned short hi;
    hi = f2bf(vp);
    dst[(h * 128 + rowp) * K + k] = hi;
    dst[256 * K + (h * 128 + rowp) * K + k] = f2bf(vp - bf2f(hi));
    hi = f2bf(vg);
    dst[(h * 128 + rowg) * K + k] = hi;
    dst[256 * K + (h * 128 + rowg) * K + k] = f2bf(vg - bf2f(hi));
}

// ---------------------------------------------------------------------------
// Stage 1: LN1 + dual GEMM (pi,gi interleaved in Wt1), A single-bf16,
// W hi/lo (2 MFMA products). LDS: 32 KiB A tile, reused for packed-u32 G.
// ---------------------------------------------------------------------------
__global__ __launch_bounds__(256, 3)
void k_stage1(const float* __restrict__ x, const float* __restrict__ mask,
              const float* __restrict__ ln1_w, const float* __restrict__ ln1_b,
              const float* __restrict__ pi_b_, const float* __restrict__ gi_b_,
              const unsigned short* __restrict__ wt1,
              unsigned short* __restrict__ wsg)
{
    __shared__ char sbuf[32768];   // A tile [128 pos][128 feat] bf16 swz; later G u32 [64 ch][128 pos]
    __shared__ float Ms[128];

    const int tid = threadIdx.x;
    const int bx = blockIdx.x;
    const int y  = blockIdx.y;
    const int o0 = y * 64;

    long posBase, outBase; int stride;
    if (y == 0) {
        posBase = ((long)(bx >> 2)) * 512 + (long)(bx & 3) * 128;
        outBase = posBase; stride = 1;
    } else {
        posBase = ((long)(bx >> 9)) * 65536 + (bx & 511);
        outBase = (long)(bx & 511) * 512 + ((bx >> 9) * 128);
        stride = 512;
    }

    // --- LN + bf16 A tile (hi only), swizzled ---
    {
        const int r = tid >> 1, hf = tid & 1;
        const float* xr = x + (posBase + (long)r * stride) * 128 + hf * 64;
        float v[64]; float s = 0.f;
#pragma unroll
        for (int q = 0; q < 16; ++q) {
            float4 t4 = ((const float4*)xr)[q];
            v[4*q+0]=t4.x; v[4*q+1]=t4.y; v[4*q+2]=t4.z; v[4*q+3]=t4.w;
            s += t4.x+t4.y+t4.z+t4.w;
        }
        s += __shfl_xor(s, 1);
        const float mu = s * (1.f/128.f);
        float vs = 0.f;
#pragma unroll
        for (int jz = 0; jz < 64; ++jz) { float d = v[jz]-mu; vs += d*d; }
        vs += __shfl_xor(vs, 1);
        const float rstd = rsqrtf(vs*(1.f/128.f) + 1e-5f);
        if (hf == 0) Ms[r] = mask[posBase + (long)r * stride];
#pragma unroll
        for (int jj = 0; jj < 8; ++jj) {
            short8 hv;
#pragma unroll
            for (int e = 0; e < 8; ++e) {
                const int f = hf*64 + jj*8 + e;
                hv[e] = (short)f2bf((v[jj*8+e]-mu)*rstd*ln1_w[f] + ln1_b[f]);
            }
            const int col = (hf*128 + jj*16) ^ ((r & 15) << 4);
            *(short8*)(sbuf + r*256 + col) = hv;
        }
    }
    __syncthreads();

    const int w = tid >> 6, l = tid & 63;
    const int mrow = (w & 1) * 64, ncol = (w >> 1) * 64;

    f32x4 acc[4][4];
#pragma unroll
    for (int m = 0; m < 4; ++m)
#pragma unroll
        for (int n = 0; n < 4; ++n) acc[m][n] = (f32x4){0.f,0.f,0.f,0.f};

#pragma unroll
    for (int step = 0; step < 4; ++step) {
        short8 ah[4], bh[4], bl[4];
#pragma unroll
        for (int n = 0; n < 4; ++n) {
            const int row = y*128 + ncol + n*16 + (l & 15);
            const int idx = row*128 + step*32 + (l >> 4)*8;
            bh[n] = *(const short8*)(wt1 + idx);
            bl[n] = *(const short8*)(wt1 + 32768 + idx);
        }
#pragma unroll
        for (int m = 0; m < 4; ++m) {
            const int pos = mrow + m*16 + (l & 15);
            const int col = (step*64 + (l >> 4)*16) ^ ((pos & 15) << 4);
            ah[m] = *(const short8*)(sbuf + pos*256 + col);
        }
#pragma unroll
        for (int m = 0; m < 4; ++m) {
#pragma unroll
            for (int n = 0; n < 4; ++n) {
                acc[m][n] = __builtin_amdgcn_mfma_f32_16x16x32_bf16(ah[m], bh[n], acc[m][n], 0, 0, 0);
                acc[m][n] = __builtin_amdgcn_mfma_f32_16x16x32_bf16(ah[m], bl[n], acc[m][n], 0, 0, 0);
            }
        }
    }
    __syncthreads();   // all A reads done; sbuf becomes G (u32-packed hi/lo)

    // --- gate (pi cols 0..7, gi cols 8..15 per fragment) + packed G write ---
    const int j = l & 15;
#pragma unroll
    for (int m = 0; m < 4; ++m) {
#pragma unroll
        for (int n = 0; n < 4; ++n) {
            const f32x4 a = acc[m][n];
            float pr[4];
#pragma unroll
            for (int e = 0; e < 4; ++e) pr[e] = __shfl_xor(a[e], 8);
            if (j < 8) {
                const int cl = (w >> 1)*32 + n*8 + j;          // 0..63 (half-local)
                const float pb = pi_b_[o0 + cl], gb = gi_b_[o0 + cl];
                const int p0 = mrow + m*16 + (l >> 4)*4;
                uint4 pk;
                uint32* pke = (uint32*)&pk;
#pragma unroll
                for (int e = 0; e < 4; ++e) {
                    const float g = (a[e] + pb) * sigmoidf_(pr[e] + gb) * Ms[p0 + e];
                    const unsigned short hi = f2bf(g);
                    const unsigned short lo = f2bf(g - bf2f(hi));
                    pke[e] = ((uint32)hi << 16) | (uint32)lo;
                }
                *(uint4*)(sbuf + cl*512 + ((p0*4) ^ ((cl & 7) << 4))) = pk;
            }
        }
    }
    __syncthreads();

    // --- cooperative plane stores: 256B-contiguous runs per plane ---
#pragma unroll
    for (int it = 0; it < 2; ++it) {
        const int u = it*256 + tid;
        const int c = u >> 3, seg = u & 7;
        unsigned short* hd = wsg + (long)(o0 + c) * NN + outBase + seg*16;
        unsigned short* ld = wsg + (long)(128 + o0 + c) * NN + outBase + seg*16;
#pragma unroll
        for (int half = 0; half < 2; ++half) {
            short8 hv, lv;
#pragma unroll
            for (int q = 0; q < 2; ++q) {
                const int b = seg*64 + half*32 + q*16;
                const uint4 w4 = *(const uint4*)(sbuf + c*512 + (b ^ ((c & 7) << 4)));
                hv[q*4+0] = (short)(w4.x >> 16); lv[q*4+0] = (short)(w4.x & 0xffffu);
                hv[q*4+1] = (short)(w4.y >> 16); lv[q*4+1] = (short)(w4.y & 0xffffu);
                hv[q*4+2] = (short)(w4.z >> 16); lv[q*4+2] = (short)(w4.z & 0xffffu);
                hv[q*4+3] = (short)(w4.w >> 16); lv[q*4+3] = (short)(w4.w & 0xffffu);
            }
            *(short8*)(hd + half*8) = hv;
            *(short8*)(ld + half*8) = lv;
        }
    }
}

// ---------------------------------------------------------------------------
// Triangular einsums (unchanged): 64 NT-GEMMs, bf16 hi/lo (3 products), MFMA.
// ---------------------------------------------------------------------------
__global__ __launch_bounds__(256, 2)
void k_einsum(const unsigned short* __restrict__ wsg, float* __restrict__ wst)
{
    const int bid = blockIdx.x;
    const int nb  = (bid & 7) * 128 + (bid >> 3);
    const int ch  = nb >> 4;
    const int bi  = (nb >> 2) & 3, bj = nb & 3;
    const int pch = (ch < 32) ? ch : ch + 32;

    const unsigned short* __restrict__ PH = wsg + (long)pch * NN;
    const unsigned short* __restrict__ PL = wsg + (long)(128 + pch) * NN;
    const unsigned short* __restrict__ QH = wsg + (long)(pch + 32) * NN;
    const unsigned short* __restrict__ QL = wsg + (long)(128 + pch + 32) * NN;
    float* __restrict__ T = wst + (long)ch * NN;

    __shared__ unsigned short smem[4 * 8192];

    const int tid = threadIdx.x;
    const int w = tid >> 6, l = tid & 63;

    int ebase[4];
#pragma unroll
    for (int j = 0; j < 4; ++j) {
        const int ci  = w * 256 + j * 64 + l;
        const int row = ci >> 3, cs = ci & 7;
        ebase[j] = row * 512 + ((cs ^ (row & 7)) << 3);
    }
    const int aOff = bi * 128 * 512;
    const int bOff = bj * 128 * 512;

    f32x4 acc[4][4];
#pragma unroll
    for (int m = 0; m < 4; ++m)
#pragma unroll
        for (int n = 0; n < 4; ++n) acc[m][n] = (f32x4){0.f, 0.f, 0.f, 0.f};

    const int mrow = (w & 1) * 64;
    const int ncol = (w >> 1) * 64;

    for (int step = 0; step < 8; ++step) {
        __syncthreads();
        const int kOff = step * 64;
#pragma unroll
        for (int j = 0; j < 4; ++j) {
            char* dst = (char*)smem + (w * 256 + j * 64) * 16;
            const unsigned short* sa_h = PH + aOff + ebase[j] + kOff;
            const unsigned short* sa_l = PL + aOff + ebase[j] + kOff;
            const unsigned short* sb_h = QH + bOff + ebase[j] + kOff;
            const unsigned short* sb_l = QL + bOff + ebase[j] + kOff;
            __builtin_amdgcn_global_load_lds((const __attribute__((address_space(1))) void*)sa_h,
                (__attribute__((address_space(3))) void*)(dst), 16, 0, 0);
            __builtin_amdgcn_global_load_lds((const __attribute__((address_space(1))) void*)sa_l,
                (__attribute__((address_space(3))) void*)(dst + 16384), 16, 0, 0);
            __builtin_amdgcn_global_load_lds((const __attribute__((address_space(1))) void*)sb_h,
                (__attribute__((address_space(3))) void*)(dst + 32768), 16, 0, 0);
            __builtin_amdgcn_global_load_lds((const __attribute__((address_space(1))) void*)sb_l,
                (__attribute__((address_space(3))) void*)(dst + 49152), 16, 0, 0);
        }
        __syncthreads();

#pragma unroll
        for (int ks = 0; ks < 2; ++ks) {
            short8 ah[4], al[4], bh[4], bl[4];
#pragma unroll
            for (int m = 0; m < 4; ++m) {
                const int r = mrow + m * 16 + (l & 15);
                const int off = r * 128 + ((((ks << 2) + (l >> 4)) ^ (r & 7)) << 4);
                ah[m] = *(const short8*)((const char*)smem + off);
                al[m] = *(const short8*)((const char*)smem + 16384 + off);
            }
#pragma unroll
            for (int n = 0; n < 4; ++n) {
                const int r = ncol + n * 16 + (l & 15);
                const int off = r * 128 + ((((ks << 2) + (l >> 4)) ^ (r & 7)) << 4);
                bh[n] = *(const short8*)((const char*)smem + 32768 + off);
                bl[n] = *(const short8*)((const char*)smem + 49152 + off);
            }
#pragma unroll
            for (int m = 0; m < 4; ++m) {
#pragma unroll
                for (int n = 0; n < 4; ++n) {
                    acc[m][n] = __builtin_amdgcn_mfma_f32_16x16x32_bf16(ah[m], bh[n], acc[m][n], 0, 0, 0);
                    acc[m][n] = __builtin_amdgcn_mfma_f32_16x16x32_bf16(ah[m], bl[n], acc[m][n], 0, 0, 0);
                    acc[m][n] = __builtin_amdgcn_mfma_f32_16x16x32_bf16(al[m], bh[n], acc[m][n], 0, 0, 0);
                }
            }
        }
    }

    const int rbase = bi * 128 + mrow;
    const int cbase = bj * 128 + ncol;
#pragma unroll
    for (int m = 0; m < 4; ++m) {
#pragma unroll
        for (int n = 0; n < 4; ++n) {
#pragma unroll
            for (int r = 0; r < 4; ++r) {
                const int row = rbase + m * 16 + (l >> 4) * 4 + r;
                const int col = cbase + n * 16 + (l & 15);
                T[(long)row * NDIM + col] = acc[m][n][r];
            }
        }
    }
}

// ---------------------------------------------------------------------------
// Stage 2: gather t planes, LN2, dual GEMM (po,go), A single-bf16, W hi/lo.
// ---------------------------------------------------------------------------
__global__ __launch_bounds__(256, 3)
void k_stage2(const float* __restrict__ wst, const float* __restrict__ mask,
              const float* __restrict__ ln2_w, const float* __restrict__ ln2_b,
              const float* __restrict__ po_b_, const float* __restrict__ go_b_,
              const unsigned short* __restrict__ wt2,
              float* __restrict__ out)
{
    __shared__ float tP[128][65];   // t gather; later reused as O[pos][ch]
    __shared__ char abuf[16384];    // A tile [128 pos][64 ch] bf16 swz
    __shared__ float Ms[128];

    const int tid = threadIdx.x;
    const long pos0 = (long)blockIdx.x * 128;
    const int y = blockIdx.y;
    const int o0 = y * 64;

    // gather 64 t planes into [pos][ch]
#pragma unroll
    for (int q = 0; q < 8; ++q) {
        const int u = q*256 + tid, d = u >> 5, p4 = u & 31;
        const float4 v = *(const float4*)(wst + (long)d * NN + pos0 + p4*4);
        tP[p4*4+0][d] = v.x; tP[p4*4+1][d] = v.y;
        tP[p4*4+2][d] = v.z; tP[p4*4+3][d] = v.w;
    }
    if (tid < 128) Ms[tid] = mask[pos0 + tid];
    __syncthreads();

    // LN2 rows -> bf16 A tile (hi only), swizzled
    {
        const int r = tid >> 1, hf = tid & 1;
        float v[32]; float s = 0.f;
#pragma unroll
        for (int jz = 0; jz < 32; ++jz) { v[jz] = tP[r][hf*32+jz]; s += v[jz]; }
        s += __shfl_xor(s, 1);
        const float mu = s * (1.f/64.f);
        float vs = 0.f;
#pragma unroll
        for (int jz = 0; jz < 32; ++jz) { float d = v[jz]-mu; vs += d*d; }
        vs += __shfl_xor(vs, 1);
        const float rstd = rsqrtf(vs*(1.f/64.f) + 1e-5f);
#pragma unroll
        for (int jj = 0; jj < 4; ++jj) {
            short8 hv;
#pragma unroll
            for (int e = 0; e < 8; ++e) {
                const int f = hf*32 + jj*8 + e;
                hv[e] = (short)f2bf((v[jj*8+e]-mu)*rstd*ln2_w[f] + ln2_b[f]);
            }
            const int col = (hf*64 + jj*16) ^ ((r & 7) << 4);
            *(short8*)(abuf + r*128 + col) = hv;
        }
    }
    __syncthreads();

    const int w = tid >> 6, l = tid & 63;
    const int mrow = (w & 1) * 64, ncol = (w >> 1) * 64;

    f32x4 acc[4][4];
#pragma unroll
    for (int m = 0; m < 4; ++m)
#pragma unroll
        for (int n = 0; n < 4; ++n) acc[m][n] = (f32x4){0.f,0.f,0.f,0.f};

#pragma unroll
    for (int step = 0; step < 2; ++step) {
        short8 ah[4], bh[4], bl[4];
#pragma unroll
        for (int n = 0; n < 4; ++n) {
            const int row = y*128 + ncol + n*16 + (l & 15);
            const int idx = row*64 + step*32 + (l >> 4)*8;
            bh[n] = *(const short8*)(wt2 + idx);
            bl[n] = *(const short8*)(wt2 + 16384 + idx);
        }
#pragma unroll
        for (int m = 0; m < 4; ++m) {
            const int pos = mrow + m*16 + (l & 15);
            const int col = (step*64 + (l >> 4)*16) ^ ((pos & 7) << 4);
            ah[m] = *(const short8*)(abuf + pos*128 + col);
        }
#pragma unroll
        for (int m = 0; m < 4; ++m) {
#pragma unroll
            for (int n = 0; n < 4; ++n) {
                acc[m][n] = __builtin_amdgcn_mfma_f32_16x16x32_bf16(ah[m], bh[n], acc[m][n], 0, 0, 0);
                acc[m][n] = __builtin_amdgcn_mfma_f32_16x16x32_bf16(ah[m], bl[n], acc[m][n], 0, 0, 0);
            }
        }
    }

    // gate + O[pos][ch] (tP dead after LN barrier)
    const int j = l & 15;
#pragma unroll
    for (int m = 0; m < 4; ++m) {
#pragma unroll
        for (int n = 0; n < 4; ++n) {
            const f32x4 a = acc[m][n];
            float pr[4];
#pragma unroll
            for (int e = 0; e < 4; ++e) pr[e] = __shfl_xor(a[e], 8);
            if (j < 8) {
                const int cl = (w >> 1)*32 + n*8 + j;
                const float pb = po_b_[o0 + cl], gb = go_b_[o0 + cl];
                const int p0 = mrow + m*16 + (l >> 4)*4;
#pragma unroll
                for (int e = 0; e < 4; ++e)
                    tP[p0 + e][cl] = (a[e] + pb) * sigmoidf_(pr[e] + gb) * Ms[p0 + e];
            }
        }
    }
    __syncthreads();

    // cooperative output stores
    {
        const int r2 = tid >> 1, h2 = tid & 1;
        float* op = out + (pos0 + r2)*128 + o0 + h2*32;
#pragma unroll
        for (int i = 0; i < 8; ++i) {
            float4 v;
            v.x = tP[r2][h2*32 + i*4 + 0];
            v.y = tP[r2][h2*32 + i*4 + 1];
            v.z = tP[r2][h2*32 + i*4 + 2];
            v.w = tP[r2][h2*32 + i*4 + 3];
            *(float4*)(op + i*4) = v;
        }
    }
}

// ---------------------------------------------------------------------------
extern "C" void kernel_launch(void* const* d_in, const int* in_sizes, int n_in,
                              void* d_out, int out_size, void* d_ws, size_t ws_size,
                              hipStream_t stream)
{
    const float* x     = (const float*)d_in[0];
    const float* mask  = (const float*)d_in[1];
    const float* ln1_w = (const float*)d_in[2];
    const float* ln1_b = (const float*)d_in[3];
    const float* pi_w  = (const float*)d_in[4];
    const float* pi_b  = (const float*)d_in[5];
    const float* gi_w  = (const float*)d_in[6];
    const float* gi_b  = (const float*)d_in[7];
    const float* ln2_w = (const float*)d_in[8];
    const float* ln2_b = (const float*)d_in[9];
    const float* po_w  = (const float*)d_in[10];
    const float* po_b  = (const float*)d_in[11];
    const float* go_w  = (const float*)d_in[12];
    const float* go_b  = (const float*)d_in[13];

    unsigned short* wsg = (unsigned short*)d_ws;              // 256 bf16 planes
    float* wst = (float*)((char*)d_ws + (long)256 * NN * 2);  // 64 fp32 planes
    unsigned short* wt1 = (unsigned short*)wst;               // transient (pre-einsum)
    unsigned short* wt2 = wsg;                                // transient (post-einsum)

    k_prep<<<64, 256, 0, stream>>>(pi_w, gi_w, 128, wt1);
    k_stage1<<<dim3(2048, 2), 256, 0, stream>>>(x, mask, ln1_w, ln1_b,
                                                pi_b, gi_b, wt1, wsg);
    k_einsum<<<1024, 256, 0, stream>>>(wsg, wst);
    k_prep<<<32, 256, 0, stream>>>(po_w, go_w, 64, wt2);
    k_stage2<<<dim3(2048, 2), 256, 0, stream>>>(wst, mask, ln2_w, ln2_b,
                                                po_b, go_b, wt2, (float*)d_out);
}